// Round 1
// baseline (91.270 us; speedup 1.0000x reference)
//
#include <hip/hip_runtime.h>
#include <hip/hip_bf16.h>

#define B 256
#define N 2048
#define D 128
#define P 2048
#define C 10
#define S_CHUNKS 16            // blocks per batch in pair kernel
#define PPB (P / S_CHUNKS)     // 128 pairs per block
#define LN_EPS 1e-5f
#define NORM_EPS 1e-12f

// ---------------------------------------------------------------------------
// Kernel 1: precompute centered, gamma-folded W1 columns and the 6 scalars of
// the variance quadratic form.
//   w0c = W1[0,:]-mean, w1c = W1[1,:]-mean, bc = b1-mean(b1)
//   wsv = {gamma*w0c, gamma*w1c, gamma*bc}   (384 floats)
//   wss = {S00,S11,Sbb,S01,S0b,S1b}          (6 floats, means of products)
// ---------------------------------------------------------------------------
__global__ void prep_kernel(const float* __restrict__ W1,
                            const float* __restrict__ b1,
                            const float* __restrict__ gamma,
                            float* __restrict__ wsv,
                            float* __restrict__ wss) {
    __shared__ float r[6][128];
    const int t = threadIdx.x;  // 128 threads
    const float w0 = W1[t], w1 = W1[128 + t], bb = b1[t];
    r[0][t] = w0; r[1][t] = w1; r[2][t] = bb;
    __syncthreads();
    for (int s = 64; s > 0; s >>= 1) {
        if (t < s) { r[0][t] += r[0][t + s]; r[1][t] += r[1][t + s]; r[2][t] += r[2][t + s]; }
        __syncthreads();
    }
    const float m0 = r[0][0] * (1.f / 128.f);
    const float m1 = r[1][0] * (1.f / 128.f);
    const float mb = r[2][0] * (1.f / 128.f);
    __syncthreads();
    const float c0 = w0 - m0, c1 = w1 - m1, cb = bb - mb;
    const float g = gamma[t];
    wsv[t]       = g * c0;
    wsv[128 + t] = g * c1;
    wsv[256 + t] = g * cb;
    r[0][t] = c0 * c0; r[1][t] = c1 * c1; r[2][t] = cb * cb;
    r[3][t] = c0 * c1; r[4][t] = c0 * cb; r[5][t] = c1 * cb;
    __syncthreads();
    for (int s = 64; s > 0; s >>= 1) {
        if (t < s) {
            #pragma unroll
            for (int q = 0; q < 6; ++q) r[q][t] += r[q][t + s];
        }
        __syncthreads();
    }
    if (t < 6) wss[t] = r[t][0] * (1.f / 128.f);
}

// ---------------------------------------------------------------------------
// Kernel 2: per-pair fused recompute.
// Grid: (S_CHUNKS, B). Block: 256 threads = 4 waves. Each wave processes one
// pair at a time: lane l owns elements d=l and d=l+64. The two row-norms are
// reduced with a 6-level __shfl_xor butterfly. Each block writes a partial
// sdi vector (128 floats) to workspace -- no atomics, fully deterministic.
// ---------------------------------------------------------------------------
__global__ __launch_bounds__(256) void pair_kernel(
        const float* __restrict__ X,
        const int*   __restrict__ pairs,
        const float* __restrict__ wsv,
        const float* __restrict__ wss,
        const float* __restrict__ beta,
        float* __restrict__ part) {
    const int s = blockIdx.x;
    const int b = blockIdx.y;
    const int tid = threadIdx.x;
    const int w = tid >> 6;      // wave id 0..3
    const int l = tid & 63;      // lane

    // per-thread element constants (d = l and d = l+64)
    const float gw0_0 = wsv[l],        gw0_1 = wsv[64 + l];
    const float gw1_0 = wsv[128 + l],  gw1_1 = wsv[192 + l];
    const float gbc_0 = wsv[256 + l],  gbc_1 = wsv[320 + l];
    const float be_0  = beta[l],       be_1  = beta[64 + l];

    // variance quadratic-form scalars (uniform)
    const float S00 = wss[0], S11 = wss[1], Sbb = wss[2];
    const float S01 = wss[3], S0b = wss[4], S1b = wss[5];

    const float2* Xb = (const float2*)(X + (size_t)b * N * 2);
    const int2*   pr = (const int2*)pairs;

    float acc0 = 0.f, acc1 = 0.f;
    const int pbase = s * PPB;

    #pragma unroll 4
    for (int t = 0; t < PPB / 4; ++t) {
        const int p = pbase + t * 4 + w;        // wave-uniform
        const int2 ij = pr[p];
        const float2 xi = Xb[ij.x];
        const float2 xj = Xb[ij.y];

        // variance via quadratic form
        const float vi = fmaf(xi.x * xi.x, S00, fmaf(xi.y * xi.y, S11, Sbb))
                       + 2.f * fmaf(xi.x * xi.y, S01, fmaf(xi.x, S0b, xi.y * S1b));
        const float vj = fmaf(xj.x * xj.x, S00, fmaf(xj.y * xj.y, S11, Sbb))
                       + 2.f * fmaf(xj.x * xj.y, S01, fmaf(xj.x, S0b, xj.y * S1b));
        const float rsi = rsqrtf(vi + LN_EPS);
        const float rsj = rsqrtf(vj + LN_EPS);

        // z rows (gamma folded into gw*, beta added after scaling)
        const float hi0 = fmaf(xi.x, gw0_0, fmaf(xi.y, gw1_0, gbc_0));
        const float hi1 = fmaf(xi.x, gw0_1, fmaf(xi.y, gw1_1, gbc_1));
        const float hj0 = fmaf(xj.x, gw0_0, fmaf(xj.y, gw1_0, gbc_0));
        const float hj1 = fmaf(xj.x, gw0_1, fmaf(xj.y, gw1_1, gbc_1));
        const float za0 = fmaxf(fmaf(hi0, rsi, be_0), 0.f);
        const float za1 = fmaxf(fmaf(hi1, rsi, be_1), 0.f);
        const float zb0 = fmaxf(fmaf(hj0, rsj, be_0), 0.f);
        const float zb1 = fmaxf(fmaf(hj1, rsj, be_1), 0.f);

        const float u0 = za0 - zb0, u1 = za1 - zb1;
        const float v0 = za0 + zb0, v1 = za1 + zb1;

        float nu = fmaf(u0, u0, u1 * u1);
        float nv = fmaf(v0, v0, v1 * v1);
        #pragma unroll
        for (int m = 1; m < 64; m <<= 1) {
            nu += __shfl_xor(nu, m, 64);
            nv += __shfl_xor(nv, m, 64);
        }
        // 1/max(sqrt(n), 1e-12) == rsqrt(max(n, 1e-24))
        const float ru = rsqrtf(fmaxf(nu, 1e-24f));
        const float rv = rsqrtf(fmaxf(nv, 1e-24f));

        acc0 = fmaf(u0, ru, fmaf(v0, rv, acc0));
        acc1 = fmaf(u1, ru, fmaf(v1, rv, acc1));
    }

    // block reduce 4 waves -> one 128-float partial
    __shared__ float red[4][128];
    red[w][l] = acc0;
    red[w][64 + l] = acc1;
    __syncthreads();
    if (tid < 128) {
        const float sum = red[0][tid] + red[1][tid] + red[2][tid] + red[3][tid];
        part[((size_t)b * S_CHUNKS + s) * 128 + tid] = sum;
    }
}

// ---------------------------------------------------------------------------
// Kernel 3: reduce partials -> sdi, write sdi out, compute MLP head + mem
// logits. One block per batch, 128 threads.
// ---------------------------------------------------------------------------
__global__ __launch_bounds__(128) void head_kernel(
        const float* __restrict__ part,
        const float* __restrict__ Wm1, const float* __restrict__ bm1,
        const float* __restrict__ Wm2, const float* __restrict__ bm2,
        const float* __restrict__ mem,
        float* __restrict__ out_logits, float* __restrict__ out_sdi) {
    const int b = blockIdx.x;
    const int t = threadIdx.x;
    __shared__ float s[128];
    __shared__ float h[128];

    float sv = 0.f;
    #pragma unroll
    for (int k = 0; k < S_CHUNKS; ++k)
        sv += part[((size_t)b * S_CHUNKS + k) * 128 + t];
    sv *= (1.f / (2.f * P));
    s[t] = sv;
    out_sdi[(size_t)b * 128 + t] = sv;
    __syncthreads();

    float a = bm1[t];
    for (int d = 0; d < 128; ++d) a = fmaf(s[d], Wm1[d * 128 + t], a);
    h[t] = fmaxf(a, 0.f);
    __syncthreads();

    if (t < C) {
        float lg = bm2[t];
        for (int d = 0; d < 128; ++d) lg = fmaf(s[d], mem[t * 128 + d], lg);
        for (int k = 0; k < 128; ++k) lg = fmaf(h[k], Wm2[k * C + t], lg);
        out_logits[(size_t)b * C + t] = lg;
    }
}

extern "C" void kernel_launch(void* const* d_in, const int* in_sizes, int n_in,
                              void* d_out, int out_size, void* d_ws, size_t ws_size,
                              hipStream_t stream) {
    const float* X     = (const float*)d_in[0];
    const int*   pairs = (const int*)  d_in[1];
    const float* W1    = (const float*)d_in[2];
    const float* b1    = (const float*)d_in[3];
    const float* gamma = (const float*)d_in[4];
    const float* beta  = (const float*)d_in[5];
    const float* Wm1   = (const float*)d_in[6];
    const float* bm1   = (const float*)d_in[7];
    const float* Wm2   = (const float*)d_in[8];
    const float* bm2   = (const float*)d_in[9];
    const float* mem   = (const float*)d_in[10];

    float* out = (float*)d_out;
    float* ws  = (float*)d_ws;
    float* wsv  = ws;          // 384 floats
    float* wss  = ws + 384;    // 6 floats (pad to 512)
    float* part = ws + 512;    // B * S_CHUNKS * 128 floats

    prep_kernel<<<1, 128, 0, stream>>>(W1, b1, gamma, wsv, wss);
    pair_kernel<<<dim3(S_CHUNKS, B), 256, 0, stream>>>(X, pairs, wsv, wss, beta, part);
    head_kernel<<<B, 128, 0, stream>>>(part, Wm1, bm1, Wm2, bm2, mem,
                                       out, out + (size_t)B * C);
}

// Round 2
// 54.599 us; speedup vs baseline: 1.6716x; 1.6716x over previous
//
#include <hip/hip_runtime.h>
#include <hip/hip_bf16.h>

#define B 256
#define N 2048
#define D 128
#define P 2048
#define C 10
#define S_CHUNKS 8             // blocks per batch in pair kernel
#define PPB (P / S_CHUNKS)     // 256 pairs per block
#define LN_EPS 1e-5f
#define NORM_EPS 1e-12f

// ---------------------------------------------------------------------------
// Kernel 1: precompute centered, gamma-folded W1 columns and the 6 scalars of
// the variance quadratic form.
// ---------------------------------------------------------------------------
__global__ void prep_kernel(const float* __restrict__ W1,
                            const float* __restrict__ b1,
                            const float* __restrict__ gamma,
                            float* __restrict__ wsv,
                            float* __restrict__ wss) {
    __shared__ float r[6][128];
    const int t = threadIdx.x;  // 128 threads
    const float w0 = W1[t], w1 = W1[128 + t], bb = b1[t];
    r[0][t] = w0; r[1][t] = w1; r[2][t] = bb;
    __syncthreads();
    for (int s = 64; s > 0; s >>= 1) {
        if (t < s) { r[0][t] += r[0][t + s]; r[1][t] += r[1][t + s]; r[2][t] += r[2][t + s]; }
        __syncthreads();
    }
    const float m0 = r[0][0] * (1.f / 128.f);
    const float m1 = r[1][0] * (1.f / 128.f);
    const float mb = r[2][0] * (1.f / 128.f);
    __syncthreads();
    const float c0 = w0 - m0, c1 = w1 - m1, cb = bb - mb;
    const float g = gamma[t];
    wsv[t]       = g * c0;
    wsv[128 + t] = g * c1;
    wsv[256 + t] = g * cb;
    r[0][t] = c0 * c0; r[1][t] = c1 * c1; r[2][t] = cb * cb;
    r[3][t] = c0 * c1; r[4][t] = c0 * cb; r[5][t] = c1 * cb;
    __syncthreads();
    for (int s = 64; s > 0; s >>= 1) {
        if (t < s) {
            #pragma unroll
            for (int q = 0; q < 6; ++q) r[q][t] += r[q][t + s];
        }
        __syncthreads();
    }
    if (t < 6) wss[t] = r[t][0] * (1.f / 128.f);
}

// ---------------------------------------------------------------------------
// 16-lane all-reduce sum via DPP butterfly (4 VALU levels, no LDS/DS pipe).
// quad_perm(1,0,3,2)=0xB1 (xor1), quad_perm(2,3,0,1)=0x4E (xor2),
// row_half_mirror=0x141 (xor7 -> other quad after quad-sum),
// row_mirror=0x140 (xor15 -> other 8-half).
// ---------------------------------------------------------------------------
__device__ __forceinline__ float red16(float x) {
    x += __int_as_float(__builtin_amdgcn_update_dpp(0, __float_as_int(x), 0xB1,  0xF, 0xF, true));
    x += __int_as_float(__builtin_amdgcn_update_dpp(0, __float_as_int(x), 0x4E,  0xF, 0xF, true));
    x += __int_as_float(__builtin_amdgcn_update_dpp(0, __float_as_int(x), 0x141, 0xF, 0xF, true));
    x += __int_as_float(__builtin_amdgcn_update_dpp(0, __float_as_int(x), 0x140, 0xF, 0xF, true));
    return x;
}

// ---------------------------------------------------------------------------
// Kernel 2: per-pair fused recompute, 4 pairs per wave.
// Grid: (S_CHUNKS, B). Block: 256 threads = 4 waves. Each wave processes 4
// pairs at a time in 16-lane groups; sublane s owns d = s + 16k, k=0..7.
// Norms reduced with the 4-level DPP butterfly. Each block writes a partial
// sdi vector (128 floats) -- no atomics, deterministic.
// ---------------------------------------------------------------------------
__global__ __launch_bounds__(256) void pair_kernel(
        const float* __restrict__ X,
        const int*   __restrict__ pairs,
        const float* __restrict__ wsv,
        const float* __restrict__ wss,
        const float* __restrict__ beta,
        float* __restrict__ part) {
    const int chunk = blockIdx.x;
    const int b = blockIdx.y;
    const int tid = threadIdx.x;
    const int w = tid >> 6;      // wave id 0..3
    const int l = tid & 63;      // lane
    const int g = l >> 4;        // 16-lane group (pair slot) 0..3
    const int s = l & 15;        // sublane = base d index

    // per-lane constants for 8 d's: d = s + 16k
    float gw0[8], gw1[8], gbc[8], be[8];
    #pragma unroll
    for (int k = 0; k < 8; ++k) {
        const int d = s + 16 * k;
        gw0[k] = wsv[d];
        gw1[k] = wsv[128 + d];
        gbc[k] = wsv[256 + d];
        be[k]  = beta[d];
    }

    // variance quadratic-form scalars (uniform)
    const float S00 = wss[0], S11 = wss[1], Sbb = wss[2];
    const float S01 = wss[3], S0b = wss[4], S1b = wss[5];

    const float2* Xb = (const float2*)(X + (size_t)b * N * 2);
    const int2*   pr = (const int2*)pairs;

    float acc[8];
    #pragma unroll
    for (int k = 0; k < 8; ++k) acc[k] = 0.f;

    const int pbase = chunk * PPB;
    const int slot = w * 4 + g;          // 0..15 pairs per block-iteration

    #pragma unroll 4
    for (int t = 0; t < PPB / 16; ++t) {
        const int p = pbase + t * 16 + slot;
        const int2 ij = pr[p];
        const float2 xi = Xb[ij.x];
        const float2 xj = Xb[ij.y];

        // variance via quadratic form (redundant across the 16 sublanes)
        const float vi = fmaf(xi.x * xi.x, S00, fmaf(xi.y * xi.y, S11, Sbb))
                       + 2.f * fmaf(xi.x * xi.y, S01, fmaf(xi.x, S0b, xi.y * S1b));
        const float vj = fmaf(xj.x * xj.x, S00, fmaf(xj.y * xj.y, S11, Sbb))
                       + 2.f * fmaf(xj.x * xj.y, S01, fmaf(xj.x, S0b, xj.y * S1b));
        const float rsi = rsqrtf(vi + LN_EPS);
        const float rsj = rsqrtf(vj + LN_EPS);

        float uu[8], vv[8];
        float nu = 0.f, nv = 0.f;
        #pragma unroll
        for (int k = 0; k < 8; ++k) {
            const float hi = fmaf(xi.x, gw0[k], fmaf(xi.y, gw1[k], gbc[k]));
            const float hj = fmaf(xj.x, gw0[k], fmaf(xj.y, gw1[k], gbc[k]));
            const float za = fmaxf(fmaf(hi, rsi, be[k]), 0.f);
            const float zb = fmaxf(fmaf(hj, rsj, be[k]), 0.f);
            const float u = za - zb, v = za + zb;
            uu[k] = u; vv[k] = v;
            nu = fmaf(u, u, nu);
            nv = fmaf(v, v, nv);
        }
        nu = red16(nu);
        nv = red16(nv);
        // 1/max(sqrt(n), 1e-12) == rsqrt(max(n, 1e-24))
        const float ru = rsqrtf(fmaxf(nu, 1e-24f));
        const float rv = rsqrtf(fmaxf(nv, 1e-24f));
        #pragma unroll
        for (int k = 0; k < 8; ++k)
            acc[k] = fmaf(uu[k], ru, fmaf(vv[k], rv, acc[k]));
    }

    // block reduce: 16 slots (4 waves x 4 groups) -> one 128-float partial
    __shared__ float red[16][8][16];     // [slot][k][s]  8 KiB
    #pragma unroll
    for (int k = 0; k < 8; ++k) red[slot][k][s] = acc[k];
    __syncthreads();
    if (tid < 128) {
        const int ss = tid & 15, kk = tid >> 4;
        float sum = 0.f;
        #pragma unroll
        for (int q = 0; q < 16; ++q) sum += red[q][kk][ss];
        part[((size_t)b * S_CHUNKS + chunk) * 128 + tid] = sum;
    }
}

// ---------------------------------------------------------------------------
// Kernel 3: reduce partials -> sdi, write sdi out, compute MLP head + mem
// logits. One block per batch, 128 threads.
// ---------------------------------------------------------------------------
__global__ __launch_bounds__(128) void head_kernel(
        const float* __restrict__ part,
        const float* __restrict__ Wm1, const float* __restrict__ bm1,
        const float* __restrict__ Wm2, const float* __restrict__ bm2,
        const float* __restrict__ mem,
        float* __restrict__ out_logits, float* __restrict__ out_sdi) {
    const int b = blockIdx.x;
    const int t = threadIdx.x;
    __shared__ float s[128];
    __shared__ float h[128];

    float sv = 0.f;
    #pragma unroll
    for (int k = 0; k < S_CHUNKS; ++k)
        sv += part[((size_t)b * S_CHUNKS + k) * 128 + t];
    sv *= (1.f / (2.f * P));
    s[t] = sv;
    out_sdi[(size_t)b * 128 + t] = sv;
    __syncthreads();

    float a = bm1[t];
    for (int d = 0; d < 128; ++d) a = fmaf(s[d], Wm1[d * 128 + t], a);
    h[t] = fmaxf(a, 0.f);
    __syncthreads();

    if (t < C) {
        float lg = bm2[t];
        for (int d = 0; d < 128; ++d) lg = fmaf(s[d], mem[t * 128 + d], lg);
        for (int k = 0; k < 128; ++k) lg = fmaf(h[k], Wm2[k * C + t], lg);
        out_logits[(size_t)b * C + t] = lg;
    }
}

extern "C" void kernel_launch(void* const* d_in, const int* in_sizes, int n_in,
                              void* d_out, int out_size, void* d_ws, size_t ws_size,
                              hipStream_t stream) {
    const float* X     = (const float*)d_in[0];
    const int*   pairs = (const int*)  d_in[1];
    const float* W1    = (const float*)d_in[2];
    const float* b1    = (const float*)d_in[3];
    const float* gamma = (const float*)d_in[4];
    const float* beta  = (const float*)d_in[5];
    const float* Wm1   = (const float*)d_in[6];
    const float* bm1   = (const float*)d_in[7];
    const float* Wm2   = (const float*)d_in[8];
    const float* bm2   = (const float*)d_in[9];
    const float* mem   = (const float*)d_in[10];

    float* out = (float*)d_out;
    float* ws  = (float*)d_ws;
    float* wsv  = ws;          // 384 floats
    float* wss  = ws + 384;    // 6 floats (pad to 512)
    float* part = ws + 512;    // B * S_CHUNKS * 128 floats

    prep_kernel<<<1, 128, 0, stream>>>(W1, b1, gamma, wsv, wss);
    pair_kernel<<<dim3(S_CHUNKS, B), 256, 0, stream>>>(X, pairs, wsv, wss, beta, part);
    head_kernel<<<B, 128, 0, stream>>>(part, Wm1, bm1, Wm2, bm2, mem,
                                       out, out + (size_t)B * C);
}

// Round 3
// 49.834 us; speedup vs baseline: 1.8315x; 1.0956x over previous
//
#include <hip/hip_runtime.h>
#include <hip/hip_bf16.h>

#define B 256
#define N 2048
#define D 128
#define P 2048
#define C 10
#define S_CHUNKS 16            // blocks per batch in pair kernel
#define PPB (P / S_CHUNKS)     // 128 pairs per block
#define LN_EPS 1e-5f
#define NORM_EPS 1e-12f

typedef float v2f __attribute__((ext_vector_type(2)));

// ---- packed fp32 VOP3P helpers (CDNA full-rate packed math) ----------------
__device__ __forceinline__ v2f pk_fma(v2f a, v2f b, v2f c) {
    v2f d;
    asm("v_pk_fma_f32 %0, %1, %2, %3" : "=v"(d) : "v"(a), "v"(b), "v"(c));
    return d;
}
__device__ __forceinline__ v2f pk_add(v2f a, v2f b) {
    v2f d;
    asm("v_pk_add_f32 %0, %1, %2" : "=v"(d) : "v"(a), "v"(b));
    return d;
}

// ---- 16-lane all-reduce sum via DPP butterfly ------------------------------
__device__ __forceinline__ float red16(float x) {
    x += __int_as_float(__builtin_amdgcn_update_dpp(0, __float_as_int(x), 0xB1,  0xF, 0xF, true));
    x += __int_as_float(__builtin_amdgcn_update_dpp(0, __float_as_int(x), 0x4E,  0xF, 0xF, true));
    x += __int_as_float(__builtin_amdgcn_update_dpp(0, __float_as_int(x), 0x141, 0xF, 0xF, true));
    x += __int_as_float(__builtin_amdgcn_update_dpp(0, __float_as_int(x), 0x140, 0xF, 0xF, true));
    return x;
}

// ---------------------------------------------------------------------------
// Kernel 1: centered, gamma-folded W1 columns + 6 variance-quadratic scalars.
// ---------------------------------------------------------------------------
__global__ void prep_kernel(const float* __restrict__ W1,
                            const float* __restrict__ b1,
                            const float* __restrict__ gamma,
                            float* __restrict__ wsv,
                            float* __restrict__ wss) {
    __shared__ float r[6][128];
    const int t = threadIdx.x;  // 128 threads
    const float w0 = W1[t], w1 = W1[128 + t], bb = b1[t];
    r[0][t] = w0; r[1][t] = w1; r[2][t] = bb;
    __syncthreads();
    for (int s = 64; s > 0; s >>= 1) {
        if (t < s) { r[0][t] += r[0][t + s]; r[1][t] += r[1][t + s]; r[2][t] += r[2][t + s]; }
        __syncthreads();
    }
    const float m0 = r[0][0] * (1.f / 128.f);
    const float m1 = r[1][0] * (1.f / 128.f);
    const float mb = r[2][0] * (1.f / 128.f);
    __syncthreads();
    const float c0 = w0 - m0, c1 = w1 - m1, cb = bb - mb;
    const float g = gamma[t];
    wsv[t]       = g * c0;
    wsv[128 + t] = g * c1;
    wsv[256 + t] = g * cb;
    r[0][t] = c0 * c0; r[1][t] = c1 * c1; r[2][t] = cb * cb;
    r[3][t] = c0 * c1; r[4][t] = c0 * cb; r[5][t] = c1 * cb;
    __syncthreads();
    for (int s = 64; s > 0; s >>= 1) {
        if (t < s) {
            #pragma unroll
            for (int q = 0; q < 6; ++q) r[q][t] += r[q][t + s];
        }
        __syncthreads();
    }
    if (t < 6) wss[t] = r[t][0] * (1.f / 128.f);
}

// ---------------------------------------------------------------------------
// Kernel 1b: per-node rsqrt(var+eps) table. One thread per (b,n).
// ---------------------------------------------------------------------------
__global__ __launch_bounds__(256) void rs_kernel(const float* __restrict__ X,
                                                 const float* __restrict__ wss,
                                                 float* __restrict__ rs) {
    const int gid = blockIdx.x * 256 + threadIdx.x;     // 0 .. B*N-1
    const float2 x = ((const float2*)X)[gid];
    const float S00 = wss[0], S11 = wss[1], Sbb = wss[2];
    const float S01 = wss[3], S0b = wss[4], S1b = wss[5];
    const float v = fmaf(x.x * x.x, S00, fmaf(x.y * x.y, S11, Sbb))
                  + 2.f * fmaf(x.x * x.y, S01, fmaf(x.x, S0b, x.y * S1b));
    rs[gid] = rsqrtf(v + LN_EPS);
}

// ---------------------------------------------------------------------------
// Kernel 2: per-pair fused recompute, 4 pairs/wave, packed fp32 math.
// Lane sublane s (0..15) owns d = s+16k, k=0..7 packed as v2f (d, d+16).
// ---------------------------------------------------------------------------
__global__ __launch_bounds__(256, 4) void pair_kernel(
        const float* __restrict__ X,
        const int*   __restrict__ pairs,
        const float* __restrict__ wsv,
        const float* __restrict__ beta,
        const float* __restrict__ rs,
        float* __restrict__ part) {
    const int chunk = blockIdx.x;
    const int b = blockIdx.y;
    const int tid = threadIdx.x;
    const int w = tid >> 6;      // wave id 0..3
    const int l = tid & 63;      // lane
    const int g = l >> 4;        // 16-lane group (pair slot in wave) 0..3
    const int s = l & 15;        // sublane = base d index

    // per-lane packed constants: m-th pair covers d = s+32m (lo), s+32m+16 (hi)
    v2f gw0[4], gw1[4], gbc[4], be2[4];
    #pragma unroll
    for (int m = 0; m < 4; ++m) {
        const int d0 = s + 32 * m;
        gw0[m] = v2f{wsv[d0],        wsv[d0 + 16]};
        gw1[m] = v2f{wsv[128 + d0],  wsv[128 + d0 + 16]};
        gbc[m] = v2f{wsv[256 + d0],  wsv[256 + d0 + 16]};
        be2[m] = v2f{beta[d0],       beta[d0 + 16]};
    }
    const v2f neg1 = v2f{-1.f, -1.f};

    const float2* Xb  = (const float2*)(X + (size_t)b * N * 2);
    const float*  rsb = rs + (size_t)b * N;
    const int2*   pr  = (const int2*)pairs;

    v2f acc[4];
    #pragma unroll
    for (int m = 0; m < 4; ++m) acc[m] = v2f{0.f, 0.f};

    const int pbase = chunk * PPB;
    const int slot = w * 4 + g;          // 0..15 pairs per block-iteration

    for (int t = 0; t < PPB / 16; ++t) {
        const int p = pbase + t * 16 + slot;
        const int2 ij = pr[p];
        const float2 xi = Xb[ij.x];
        const float2 xj = Xb[ij.y];
        const float rsi = rsb[ij.x];
        const float rsj = rsb[ij.y];

        const v2f xix = v2f{xi.x, xi.x}, xiy = v2f{xi.y, xi.y};
        const v2f xjx = v2f{xj.x, xj.x}, xjy = v2f{xj.y, xj.y};
        const v2f rsi2 = v2f{rsi, rsi},  rsj2 = v2f{rsj, rsj};

        v2f uu[4], vv[4];
        v2f nu2 = v2f{0.f, 0.f}, nv2 = v2f{0.f, 0.f};
        #pragma unroll
        for (int m = 0; m < 4; ++m) {
            const v2f hi = pk_fma(xix, gw0[m], pk_fma(xiy, gw1[m], gbc[m]));
            const v2f hj = pk_fma(xjx, gw0[m], pk_fma(xjy, gw1[m], gbc[m]));
            const v2f ti = pk_fma(hi, rsi2, be2[m]);
            const v2f tj = pk_fma(hj, rsj2, be2[m]);
            const v2f za = v2f{fmaxf(ti.x, 0.f), fmaxf(ti.y, 0.f)};
            const v2f zb = v2f{fmaxf(tj.x, 0.f), fmaxf(tj.y, 0.f)};
            const v2f u = pk_fma(zb, neg1, za);   // za - zb
            const v2f v = pk_add(za, zb);         // za + zb
            nu2 = pk_fma(u, u, nu2);
            nv2 = pk_fma(v, v, nv2);
            uu[m] = u; vv[m] = v;
        }
        float nu = nu2.x + nu2.y;
        float nv = nv2.x + nv2.y;
        nu = red16(nu);
        nv = red16(nv);
        const float ru = rsqrtf(fmaxf(nu, 1e-24f));
        const float rv = rsqrtf(fmaxf(nv, 1e-24f));
        const v2f ru2 = v2f{ru, ru}, rv2 = v2f{rv, rv};
        #pragma unroll
        for (int m = 0; m < 4; ++m)
            acc[m] = pk_fma(uu[m], ru2, pk_fma(vv[m], rv2, acc[m]));
    }

    // block reduce: 16 slots -> one 128-float partial (padded: no conflicts)
    __shared__ float red[16][8][17];
    #pragma unroll
    for (int m = 0; m < 4; ++m) {
        red[slot][2 * m    ][s] = acc[m].x;   // d = s + 32m
        red[slot][2 * m + 1][s] = acc[m].y;   // d = s + 32m + 16
    }
    __syncthreads();
    if (tid < 128) {
        const int ss = tid & 15, kk = tid >> 4;   // d = ss + 16*kk == tid
        float sum = 0.f;
        #pragma unroll
        for (int q = 0; q < 16; ++q) sum += red[q][kk][ss];
        part[((size_t)b * S_CHUNKS + chunk) * 128 + tid] = sum;
    }
}

// ---------------------------------------------------------------------------
// Kernel 3: reduce partials -> sdi, MLP head + mem logits. 256 threads/block.
// ---------------------------------------------------------------------------
__global__ __launch_bounds__(256) void head_kernel(
        const float* __restrict__ part,
        const float* __restrict__ Wm1, const float* __restrict__ bm1,
        const float* __restrict__ Wm2, const float* __restrict__ bm2,
        const float* __restrict__ mem,
        float* __restrict__ out_logits, float* __restrict__ out_sdi) {
    const int b = blockIdx.x;
    const int t = threadIdx.x;
    __shared__ float s[128];
    __shared__ float h[128];

    if (t < 128) {
        float sv = 0.f;
        #pragma unroll
        for (int k = 0; k < S_CHUNKS; ++k)
            sv += part[((size_t)b * S_CHUNKS + k) * 128 + t];
        sv *= (1.f / (2.f * P));
        s[t] = sv;
        out_sdi[(size_t)b * 128 + t] = sv;
    }
    __syncthreads();
    if (t < 128) {
        float a = bm1[t];
        for (int d = 0; d < 128; ++d) a = fmaf(s[d], Wm1[d * 128 + t], a);
        h[t] = fmaxf(a, 0.f);
    }
    __syncthreads();
    if (t < 16 * C) {                       // 160 threads: 16 lanes per class
        const int c = t >> 4, l = t & 15;
        float lg = 0.f;
        #pragma unroll
        for (int q = 0; q < 8; ++q) {
            const int d = l + 16 * q;
            lg = fmaf(s[d], mem[c * 128 + d], fmaf(h[d], Wm2[d * C + c], lg));
        }
        lg = red16(lg);
        if (l == 0) out_logits[(size_t)b * C + c] = lg + bm2[c];
    }
}

extern "C" void kernel_launch(void* const* d_in, const int* in_sizes, int n_in,
                              void* d_out, int out_size, void* d_ws, size_t ws_size,
                              hipStream_t stream) {
    const float* X     = (const float*)d_in[0];
    const int*   pairs = (const int*)  d_in[1];
    const float* W1    = (const float*)d_in[2];
    const float* b1    = (const float*)d_in[3];
    const float* gamma = (const float*)d_in[4];
    const float* beta  = (const float*)d_in[5];
    const float* Wm1   = (const float*)d_in[6];
    const float* bm1   = (const float*)d_in[7];
    const float* Wm2   = (const float*)d_in[8];
    const float* bm2   = (const float*)d_in[9];
    const float* mem   = (const float*)d_in[10];

    float* out = (float*)d_out;
    float* ws  = (float*)d_ws;
    float* wsv  = ws;                        // 384 floats
    float* wss  = ws + 384;                  // 6 floats (pad to 512)
    float* rs   = ws + 512;                  // B*N floats (524288)
    float* part = rs + (size_t)B * N;        // B*S_CHUNKS*128 floats (524288)

    prep_kernel<<<1, 128, 0, stream>>>(W1, b1, gamma, wsv, wss);
    rs_kernel<<<(B * N) / 256, 256, 0, stream>>>(X, wss, rs);
    pair_kernel<<<dim3(S_CHUNKS, B), 256, 0, stream>>>(X, pairs, wsv, beta, rs, part);
    head_kernel<<<B, 256, 0, stream>>>(part, Wm1, bm1, Wm2, bm2, mem,
                                       out, out + (size_t)B * C);
}